// Round 13
// baseline (1714.879 us; speedup 1.0000x reference)
//
#include <hip/hip_runtime.h>

// LSTM (B=256, T=256, F=128, H=1024) + sigmoid + FC(1024->128).
// Persistent 256-WG x 256-thread kernel (4 waves, 1 wave/SIMD).
// R13: two interleaved half-batch groups (A: rows 0..127, B: rows 128..255)
// sharing register-resident W; fp8 h exchange (R12-proven dq/permute/scale);
// checksum-speculative sync with proven flag fallback.
//
// Tiling: WG (rg=wg>>5, cg=wg&31) owns, PER GROUP, a 16-row x 128-gatecol
// tile: rows g*128 + rg*16 .. +16, gate cols {n*1024 + cg*32 .. +32}.
// MFMA mfma_f32_16x16x32_f16: A lane row=l&15, k=(l>>4)*8+j; B col=l&15,
// same k; C col=l&15, row=(l>>4)*4+reg [m89/m91]. Wave w K-split: h-K
// [w*256,+256) = 8 chunks of 32, x-K [w*32,+32) = 1 chunk (q=8).
//
// h exchange: hb[g][slot 0..3][rg][16 rows][1024 cols] fp8 (code: sign |
// f16bits(v/256)[13:7]; dq -> f16 patterns worth v/256; W packed as 256*W
// with k-permutation P={0,2,1,3,4,6,5,7} folding dq's pair order; xT=x/256).
// Producer tile = 16x32 = 512B + u32 hash (mul-mix over the exact bytes in
// consumer-lane order, salted by pos 0..7 and epoch).
//
// Sync per phase: speculative load (issued ONE PHASE EARLY) + in-register
// verify; <=2 tries then proven per-wave flag poll (flags set once per step
// after a vmcnt(0) drain). 4 rotating slots per group; WAR safe under both
// evidence paths (verified-data or flag transitivity: seeing step-s data/flag
// from all 32 cohort members implies their reads of step s-1 finished).

typedef _Float16 f16x8 __attribute__((ext_vector_type(8)));
typedef float f32x4 __attribute__((ext_vector_type(4)));
typedef unsigned long long u64;
typedef unsigned u32;

#define SCOPE_AGENT __HIP_MEMORY_SCOPE_AGENT

#define WS_WP    0ull
#define WS_BIAS  9437184ull
#define WS_XT    (WS_BIAS + 16384ull)
#define WS_HB    (WS_XT + 16777216ull)          // 2g x 4slot x 8rg x 16KB = 1MB
#define WS_HASH  (WS_HB + 1048576ull)           // 2x4x8x32 u32 = 8KB
#define WS_SIGH  (WS_HASH + 8192ull)
#define WS_BAR   (WS_SIGH + 1048576ull)         // flagsA[256], flagsB[256]

__device__ __forceinline__ unsigned short f2h(float f) {
  _Float16 h = (_Float16)f;
  return __builtin_bit_cast(unsigned short, h);
}
__device__ __forceinline__ float fast_sig(float x) {
  return __builtin_amdgcn_rcpf(1.f + __expf(-x));
}
__device__ __forceinline__ float fast_tanh(float x) {
  return __builtin_fmaf(2.f, fast_sig(2.f * x), -1.f);
}
// h fp8 encode: v in (-1,1) -> byte = sign | RNE(f16bits(v/256))[13:7]
__device__ __forceinline__ unsigned char h_enc(float v) {
  _Float16 gh = (_Float16)(v * 0.00390625f);
  unsigned m = __builtin_bit_cast(unsigned short, gh);
  unsigned r = m + 0x3fu + ((m >> 7) & 1u);
  return (unsigned char)(((m >> 8) & 0x80u) | ((r >> 7) & 0x7fu));
}
// dequant 8 fp8 bytes -> f16x8 patterns worth v/256, element order
// {b0,b2,b1,b3,b4,b6,b5,b7} (W pack applies same k-permutation).
__device__ __forceinline__ f16x8 dq(u64 v) {
  unsigned w0 = (unsigned)v, w1 = (unsigned)(v >> 32);
  unsigned e0 = w0 & 0x00ff00ffu, o0 = (w0 >> 8) & 0x00ff00ffu;
  unsigned e1 = w1 & 0x00ff00ffu, o1 = (w1 >> 8) & 0x00ff00ffu;
  int4 t;
  t.x = (int)((e0 + (e0 & 0x00800080u)) << 7);
  t.y = (int)((o0 + (o0 & 0x00800080u)) << 7);
  t.z = (int)((e1 + (e1 & 0x00800080u)) << 7);
  t.w = (int)((o1 + (o1 & 0x00800080u)) << 7);
  return __builtin_bit_cast(f16x8, t);
}

// ---- checksum primitives (identical byte-mapping on both sides) ----
__device__ __forceinline__ u32 fold64(u64 v) {
  return (u32)v ^ ((u32)(v >> 32) * 0x85EBCA77u);
}
#define HASH_INIT(EP, POS) (0x9E3779B9u * (u32)(EP) + (u32)(POS) * 0x7FEB352Du + 0x165667B1u)
#define HASH_STEP(H, V, R)  ((((H) ^ fold64(V)) * 0x9E3779B1u) + (u32)(R))

// Pack 256*W_cat into per-(cg,w,ct,q,lane) 16x16x32 MFMA B-fragments (fp16).
// i = ((((cg*4 + w)*8 + ct)*9 + q)*64 + l)*8 + j
//   gcol = (ct>>1)*1024 + cg*32 + (ct&1)*16 + (l&15); khi = (l>>4)*8
//   q<8 (h, PERMUTED j): k = w*256 + q*32 + khi + P[j] -> W_hh[gcol][k]
//   q=8 (x, natural j):  f = w*32 + khi + j           -> W_ih[gcol][f]
__global__ void prep_pack(const float* __restrict__ W_ih, const float* __restrict__ W_hh,
                          const float* __restrict__ b_ih, const float* __restrict__ b_hh,
                          unsigned short* __restrict__ wp, float* __restrict__ bias) {
  unsigned i = blockIdx.x * 256u + threadIdx.x;
  if (i < 4718592u) {
    unsigned j = i & 7u;
    unsigned l = (i >> 3) & 63u;
    unsigned rest = i >> 9;
    unsigned q = rest % 9u;
    unsigned rest2 = rest / 9u;
    unsigned ct = rest2 & 7u;
    unsigned rest3 = rest2 >> 3;
    unsigned w = rest3 & 3u;
    unsigned cg = rest3 >> 2;
    unsigned gcol = (ct >> 1) * 1024u + cg * 32u + (ct & 1u) * 16u + (l & 15u);
    unsigned khi = (l >> 4) * 8u;
    float v;
    if (q < 8u) {
      unsigned pj = (0x75643120u >> (4u * j)) & 0xfu;   // {0,2,1,3,4,6,5,7}
      unsigned k = w * 256u + q * 32u + khi + pj;
      v = W_hh[(size_t)gcol * 1024u + k];
    } else {
      unsigned f = w * 32u + khi + j;
      v = W_ih[(size_t)gcol * 128u + f];
    }
    wp[i] = f2h(v * 256.0f);
  }
  if (i < 4096u) bias[i] = b_ih[i] + b_hh[i];
}

// xT[t][b][f] = fp16(x/256) ; h0 -> fp8 hb slot0 both groups ; zero flags.
__global__ void prep_misc(const float* __restrict__ x, const float* __restrict__ h0,
                          unsigned short* __restrict__ xT, unsigned char* __restrict__ hb,
                          unsigned* __restrict__ bar) {
  unsigned i = blockIdx.x * 256u + threadIdx.x;
  if (i < 8388608u) {
    unsigned f = i & 127u;
    unsigned b = (i >> 7) & 255u;
    unsigned t = i >> 15;
    xT[i] = f2h(x[((size_t)b * 256u + t) * 128u + f] * 0.00390625f);
  }
  if (i < 262144u) {
    unsigned col = i & 1023u;
    unsigned grow = i >> 10;          // global batch row
    unsigned g = grow >> 7;
    unsigned rg = (grow >> 4) & 7u;
    unsigned row = grow & 15u;
    hb[((g * 4u + 0u) * 8u + rg) * 16384u + row * 1024u + col] = h_enc(h0[i]);
  }
  if (i < 512u) bar[i] = 0u;
}

// Seed epoch-0 hashes over hb slot0 (must match consumer fold exactly).
__global__ void prep_hash(const unsigned char* __restrict__ hb, unsigned* __restrict__ hashes) {
  unsigned id = blockIdx.x * 256u + threadIdx.x;
  if (id >= 512u) return;
  unsigned g = id >> 8, rg = (id >> 5) & 7u, cg = id & 31u;
  const unsigned char* base = hb + ((g * 4u + 0u) * 8u + rg) * 16384u;
  u32 tile = 0u;
  for (unsigned pos = 0; pos < 8u; ++pos) {
    u32 h = HASH_INIT(0u, pos);
    for (unsigned r = 0; r < 8u; ++r) {
      u64 v = *(const u64*)(base + ((pos >> 2) + 2u * r) * 1024u + cg * 32u + (pos & 3u) * 8u);
      h = HASH_STEP(h, v, r);
    }
    tile ^= h;
  }
  hashes[((g * 4u + 0u) * 8u + rg) * 32u + cg] = tile;
}

#define SPEC_LOAD(SA, HA, G, SLOT) do {                                          \
    const char* _b = (const char*)hbase + (((G)*4u + (SLOT))*8u + rg)*16384u     \
                     + hi*1024u + w*256u + lo5*8u;                               \
    for (int _r = 0; _r < 8; ++_r)                                               \
      SA[_r] = __hip_atomic_load((const u64*)(_b + (unsigned)_r*2048u),          \
                                 __ATOMIC_RELAXED, SCOPE_AGENT);                 \
    HA = __hip_atomic_load(hashes + (((G)*4u + (SLOT))*8u + rg)*32u              \
                           + w*8u + (lo5 >> 2), __ATOMIC_RELAXED, SCOPE_AGENT);  \
  } while (0)

#define VERIFY(SA, HA, EPOCH, OK) do {                                           \
    u32 _h = HASH_INIT((EPOCH), pos);                                            \
    for (int _r = 0; _r < 8; ++_r) _h = HASH_STEP(_h, SA[_r], _r);               \
    _h ^= (u32)__shfl_xor((int)_h, 1, 64);                                       \
    _h ^= (u32)__shfl_xor((int)_h, 2, 64);                                       \
    _h ^= (u32)__shfl_xor((int)_h, 32, 64);                                      \
    OK = __all(_h == (HA));                                                      \
  } while (0)

#define POLL(FL, TGT) do {                                                       \
    for (;;) {                                                                   \
      unsigned _f = __hip_atomic_load((FL) + w*8u + (l & 7u),                    \
                                      __ATOMIC_RELAXED, SCOPE_AGENT);            \
      if (__all(_f >= (TGT))) break;                                             \
      __builtin_amdgcn_s_sleep(1);                                               \
    }                                                                            \
  } while (0)

__launch_bounds__(256, 1)
__global__ void lstm_main(const unsigned short* __restrict__ wp,
                          const float* __restrict__ bias,
                          const unsigned short* __restrict__ xT,
                          unsigned char* __restrict__ hb,
                          unsigned* __restrict__ hashes,
                          const float* __restrict__ c0,
                          float* __restrict__ sigh,
                          unsigned* __restrict__ bar) {
  extern __shared__ char lds[];
  // [0,16K): per-wave fp8 stage (w*4KB, [16 rows][256B], XOR-swz (row&7)<<3)
  // [16K,48K): reduce [wo4][ct8][l64] float4   [48K..]: hstA 512B, hstB 512B
  float4* redv = (float4*)(lds + 16384);
  float*  redf = (float*)(lds + 16384);
  unsigned char* hstA = (unsigned char*)(lds + 49152);
  unsigned char* hstB = (unsigned char*)(lds + 49664);

  const unsigned tid = threadIdx.x;
  const unsigned wg  = blockIdx.x;
  const unsigned w   = tid >> 6;
  const unsigned l   = tid & 63u;
  const unsigned rg  = wg >> 5;
  const unsigned cg  = wg & 31u;
  const unsigned lo5 = l & 31u;
  const unsigned hi  = l >> 5;
  const unsigned l15 = l & 15u;
  const unsigned l4  = l >> 4;
  const unsigned pos = (hi << 2) | (lo5 & 3u);
  const unsigned row = l4 * 4u + w;            // cell row 0..15

  // ---- register-resident W fragments (72 x int4) ----
  int4 Braw[8][9];
  {
    const int4* wpv = (const int4*)wp;
    const unsigned wbase = (cg * 4u + w) * 4608u;
#pragma unroll
    for (int ct = 0; ct < 8; ++ct)
#pragma unroll
      for (int q = 0; q < 9; ++q)
        Braw[ct][q] = wpv[wbase + (unsigned)(ct * 9 + q) * 64u + l];
  }

  float bias_v[8];
#pragma unroll
  for (int ct = 0; ct < 8; ++ct)
    bias_v[ct] = bias[(unsigned)(ct >> 1) * 1024u + cg * 32u + (unsigned)(ct & 1) * 16u + l15];

  const unsigned gbA = rg * 16u, gbB = 128u + rg * 16u;
  float cA[2], cB[2];
  unsigned soffA[2], soffB[2];
#pragma unroll
  for (int hh = 0; hh < 2; ++hh) {
    soffA[hh] = (gbA + row) * 1024u + cg * 32u + (unsigned)hh * 16u + l15;
    soffB[hh] = (gbB + row) * 1024u + cg * 32u + (unsigned)hh * 16u + l15;
    cA[hh] = c0[soffA[hh]];
    cB[hh] = c0[soffB[hh]];
  }

  const char* xbase = (const char*)xT;
  const unsigned xoffA = ((gbA + l15) * 128u + w * 32u + l4 * 8u) * 2u;
  const unsigned xoffB = ((gbB + l15) * 128u + w * 32u + l4 * 8u) * 2u;
  unsigned char* hbase = hb;
  unsigned* flagsA = &bar[rg * 32u];
  unsigned* flagsB = &bar[256u + rg * 32u];

  const unsigned fb = w * 4096u + l15 * 256u + l4 * 8u;   // frag base
  const unsigned fx = (l15 & 7u) << 3;

  u64 saA[8], saB[8];
  u32 haA, haB;
  int4 xrA, xrB;

  // prologue: speculative A(0) + x(0) loads
  SPEC_LOAD(saA, haA, 0u, 0u);
  xrA = *(const int4*)(xbase + xoffA);
  xrB = *(const int4*)(xbase + xoffB);

  for (unsigned t = 0; t < 256u; ++t) {
    const bool last = (t == 255u);
    const unsigned slot = t & 3u, wslot = (t + 1u) & 3u;

    // ================= PHASE A =================
    {
      bool ok; VERIFY(saA, haA, t, ok);
      if (!ok) {
        SPEC_LOAD(saA, haA, 0u, slot);
        VERIFY(saA, haA, t, ok);
        if (!ok) { POLL(flagsA, t); SPEC_LOAD(saA, haA, 0u, slot); }
      }
    }
    // speculative B(t) issue (data stored by producers ~1 phase ago)
    SPEC_LOAD(saB, haB, 1u, slot);

    // stage A -> LDS (swizzled), then MFMA
#pragma unroll
    for (int r = 0; r < 8; ++r) {
      unsigned d = w * 4096u + (hi + 2u * (unsigned)r) * 256u + lo5 * 8u;
      *(u64*)(lds + (d ^ (((d >> 8) & 7u) << 3))) = saA[r];
    }
    f32x4 acc[8] = {};
    {
      f16x8 a = __builtin_bit_cast(f16x8, xrA);
#pragma unroll
      for (int ct = 0; ct < 8; ++ct)
        acc[ct] = __builtin_amdgcn_mfma_f32_16x16x32_f16(a, __builtin_bit_cast(f16x8, Braw[ct][8]), acc[ct], 0, 0, 0);
    }
#pragma unroll
    for (int q = 0; q < 8; ++q) {
      u64 hv = *(const u64*)(lds + ((fb + (unsigned)q * 32u) ^ fx));
      f16x8 a = dq(hv);
#pragma unroll
      for (int ct = 0; ct < 8; ++ct)
        acc[ct] = __builtin_amdgcn_mfma_f32_16x16x32_f16(a, __builtin_bit_cast(f16x8, Braw[ct][q]), acc[ct], 0, 0, 0);
    }
    // reduce A
#pragma unroll
    for (int ct = 0; ct < 8; ++ct) {
      float4 v; v.x = acc[ct][0]; v.y = acc[ct][1]; v.z = acc[ct][2]; v.w = acc[ct][3];
      redv[(w * 8u + (unsigned)ct) * 64u + l] = v;
    }
    __syncthreads();
    float gv[8];
#pragma unroll
    for (int ct = 0; ct < 8; ++ct) {
      float s = bias_v[ct];
#pragma unroll
      for (int wo = 0; wo < 4; ++wo)
        s += redf[(((unsigned)wo * 8u + (unsigned)ct) * 64u + l) * 4u + w];
      gv[ct] = s;
    }
    // cell A (row, 2 hcol-halves)
#pragma unroll
    for (int hh = 0; hh < 2; ++hh) {
      float ig = fast_sig(gv[0 * 2 + hh]);
      float fg = fast_sig(gv[1 * 2 + hh]);
      float gg = fast_tanh(gv[2 * 2 + hh]);
      float og = fast_sig(gv[3 * 2 + hh]);
      float cc = fg * cA[hh] + ig * gg;
      cA[hh] = cc;
      float hhv = og * fast_tanh(cc);
      hstA[row * 32u + (unsigned)hh * 16u + l15] = h_enc(hhv);
      if (last) sigh[soffA[hh]] = fast_sig(hhv);
    }
    __syncthreads();   // hstA complete (also orders reduce reads vs B writes)
    if (!last) {
      // store A data (128 threads x 4B) + hash (wave0 lanes 0..7)
      if (tid < 128u) {
        unsigned v = *(const unsigned*)(hstA + (tid >> 3) * 32u + (tid & 7u) * 4u);
        char* dst = (char*)hbase + ((0u * 4u + wslot) * 8u + rg) * 16384u
                    + (tid >> 3) * 1024u + cg * 32u + (tid & 7u) * 4u;
        __hip_atomic_store((unsigned*)dst, v, __ATOMIC_RELAXED, SCOPE_AGENT);
      }
      if (tid < 8u) {
        u32 h = HASH_INIT(t + 1u, tid);
#pragma unroll
        for (int r = 0; r < 8; ++r) {
          u64 v = *(const u64*)(hstA + ((tid >> 2) + 2u * (unsigned)r) * 32u + (tid & 3u) * 8u);
          h = HASH_STEP(h, v, r);
        }
        h ^= (u32)__shfl_xor((int)h, 1, 64);
        h ^= (u32)__shfl_xor((int)h, 2, 64);
        h ^= (u32)__shfl_xor((int)h, 4, 64);
        if (tid == 0u)
          __hip_atomic_store(hashes + ((0u * 4u + wslot) * 8u + rg) * 32u + cg, h,
                             __ATOMIC_RELAXED, SCOPE_AGENT);
      }
    }

    // ================= PHASE B =================
    {
      bool ok; VERIFY(saB, haB, t, ok);
      if (!ok) {
        SPEC_LOAD(saB, haB, 1u, slot);
        VERIFY(saB, haB, t, ok);
        if (!ok) { POLL(flagsB, t); SPEC_LOAD(saB, haB, 1u, slot); }
      }
    }
    if (!last) {
      // speculative A(t+1) + x(t+1) issue
      SPEC_LOAD(saA, haA, 0u, wslot);
      xrA = *(const int4*)(xbase + xoffA + (t + 1u) * 65536u);
    }

#pragma unroll
    for (int r = 0; r < 8; ++r) {
      unsigned d = w * 4096u + (hi + 2u * (unsigned)r) * 256u + lo5 * 8u;
      *(u64*)(lds + (d ^ (((d >> 8) & 7u) << 3))) = saB[r];
    }
    f32x4 accB[8] = {};
    {
      f16x8 a = __builtin_bit_cast(f16x8, xrB);
#pragma unroll
      for (int ct = 0; ct < 8; ++ct)
        accB[ct] = __builtin_amdgcn_mfma_f32_16x16x32_f16(a, __builtin_bit_cast(f16x8, Braw[ct][8]), accB[ct], 0, 0, 0);
    }
#pragma unroll
    for (int q = 0; q < 8; ++q) {
      u64 hv = *(const u64*)(lds + ((fb + (unsigned)q * 32u) ^ fx));
      f16x8 a = dq(hv);
#pragma unroll
      for (int ct = 0; ct < 8; ++ct)
        accB[ct] = __builtin_amdgcn_mfma_f32_16x16x32_f16(a, __builtin_bit_cast(f16x8, Braw[ct][q]), accB[ct], 0, 0, 0);
    }
    __syncthreads();   // prior reduce reads done before overwrite
#pragma unroll
    for (int ct = 0; ct < 8; ++ct) {
      float4 v; v.x = accB[ct][0]; v.y = accB[ct][1]; v.z = accB[ct][2]; v.w = accB[ct][3];
      redv[(w * 8u + (unsigned)ct) * 64u + l] = v;
    }
    __syncthreads();
#pragma unroll
    for (int ct = 0; ct < 8; ++ct) {
      float s = bias_v[ct];
#pragma unroll
      for (int wo = 0; wo < 4; ++wo)
        s += redf[(((unsigned)wo * 8u + (unsigned)ct) * 64u + l) * 4u + w];
      gv[ct] = s;
    }
#pragma unroll
    for (int hh = 0; hh < 2; ++hh) {
      float ig = fast_sig(gv[0 * 2 + hh]);
      float fg = fast_sig(gv[1 * 2 + hh]);
      float gg = fast_tanh(gv[2 * 2 + hh]);
      float og = fast_sig(gv[3 * 2 + hh]);
      float cc = fg * cB[hh] + ig * gg;
      cB[hh] = cc;
      float hhv = og * fast_tanh(cc);
      hstB[row * 32u + (unsigned)hh * 16u + l15] = h_enc(hhv);
      if (last) sigh[soffB[hh]] = fast_sig(hhv);
    }
    __syncthreads();   // hstB complete
    if (!last) {
      if (tid < 128u) {
        unsigned v = *(const unsigned*)(hstB + (tid >> 3) * 32u + (tid & 7u) * 4u);
        char* dst = (char*)hbase + ((1u * 4u + wslot) * 8u + rg) * 16384u
                    + (tid >> 3) * 1024u + cg * 32u + (tid & 7u) * 4u;
        __hip_atomic_store((unsigned*)dst, v, __ATOMIC_RELAXED, SCOPE_AGENT);
      }
      if (tid < 8u) {
        u32 h = HASH_INIT(t + 1u, tid);
#pragma unroll
        for (int r = 0; r < 8; ++r) {
          u64 v = *(const u64*)(hstB + ((tid >> 2) + 2u * (unsigned)r) * 32u + (tid & 3u) * 8u);
          h = HASH_STEP(h, v, r);
        }
        h ^= (u32)__shfl_xor((int)h, 1, 64);
        h ^= (u32)__shfl_xor((int)h, 2, 64);
        h ^= (u32)__shfl_xor((int)h, 4, 64);
        if (tid == 0u)
          __hip_atomic_store(hashes + ((1u * 4u + wslot) * 8u + rg) * 32u + cg, h,
                             __ATOMIC_RELAXED, SCOPE_AGENT);
      }
      // prefetch xB(t+1)
      xrB = *(const int4*)(xbase + xoffB + (t + 1u) * 65536u);
      // end-of-step: drain (vmcnt0 in barrier lowering) + proven flags
      __syncthreads();
      if (tid == 0u) {
        __hip_atomic_store(&flagsA[cg], t + 1u, __ATOMIC_RELAXED, SCOPE_AGENT);
        __hip_atomic_store(&flagsB[cg], t + 1u, __ATOMIC_RELAXED, SCOPE_AGENT);
      }
    }
  }
}

// out[b][o] = b_fc[o] + sum_k sigh[b][k] * W_fc[o][k]
__global__ void final_fc(const float* __restrict__ sigh, const float* __restrict__ W_fc,
                         const float* __restrict__ b_fc, float* __restrict__ out) {
  unsigned b = blockIdx.x;
  unsigned o = threadIdx.x;
  const float* hrow = sigh + (size_t)b * 1024u;
  const float* wrow = W_fc + (size_t)o * 1024u;
  float acc = b_fc[o];
#pragma unroll 8
  for (unsigned k = 0; k < 1024u; k += 4u) {
    float4 hv = *(const float4*)(hrow + k);
    float4 wv = *(const float4*)(wrow + k);
    acc += hv.x * wv.x + hv.y * wv.y + hv.z * wv.z + hv.w * wv.w;
  }
  out[b * 128u + o] = acc;
}

extern "C" void kernel_launch(void* const* d_in, const int* in_sizes, int n_in,
                              void* d_out, int out_size, void* d_ws, size_t ws_size,
                              hipStream_t stream) {
  (void)in_sizes; (void)n_in; (void)out_size; (void)ws_size;
  const float* x    = (const float*)d_in[0];
  const float* h0   = (const float*)d_in[1];
  const float* c0   = (const float*)d_in[2];
  const float* W_ih = (const float*)d_in[3];
  const float* W_hh = (const float*)d_in[4];
  const float* b_ih = (const float*)d_in[5];
  const float* b_hh = (const float*)d_in[6];
  const float* W_fc = (const float*)d_in[7];
  const float* b_fc = (const float*)d_in[8];

  char* ws = (char*)d_ws;
  unsigned short* wp   = (unsigned short*)(ws + WS_WP);
  float*          bias = (float*)(ws + WS_BIAS);
  unsigned short* xT   = (unsigned short*)(ws + WS_XT);
  unsigned char*  hb   = (unsigned char*)(ws + WS_HB);
  unsigned*       hashes = (unsigned*)(ws + WS_HASH);
  float*          sigh = (float*)(ws + WS_SIGH);
  unsigned*       bar  = (unsigned*)(ws + WS_BAR);
  float*          out  = (float*)d_out;

  prep_pack<<<18432, 256, 0, stream>>>(W_ih, W_hh, b_ih, b_hh, wp, bias);
  prep_misc<<<32768, 256, 0, stream>>>(x, h0, xT, hb, bar);
  prep_hash<<<2, 256, 0, stream>>>(hb, hashes);
  lstm_main<<<256, 256, 50176, stream>>>(wp, bias, xT, hb, hashes, c0, sigh, bar);
  final_fc<<<256, 128, 0, stream>>>(sigh, W_fc, b_fc, out);
}

// Round 14
// 1506.363 us; speedup vs baseline: 1.1384x; 1.1384x over previous
//
#include <hip/hip_runtime.h>

// LSTM (B=256, T=256, F=128, H=1024) + sigmoid + FC(1024->128).
// Persistent 256-WG x 256-thread kernel (4 waves, 1 wave/SIMD).
// R14 = R13's G=2 interleave skeleton (two half-batch groups A: rows 0..127,
// B: rows 128..255 time-sharing register-resident W) with the taxes removed:
// no checksums (flag-only, one check/step, loads issued early and hidden
// under compute epilogues), LDS-only barriers (lgkmcnt + raw s_barrier) so
// in-flight global loads survive intra-step syncs, conflict-free two-stage
// reduce (SoA-by-reg), full-width frag swizzle (kbyte ^ (row&15)<<3).
//
// WG (rg=wg>>5, cg=wg&31) owns per group a 16-row x 128-gatecol tile:
// rows g*128 + rg*16..+16, gate cols {n*1024 + cg*32..+32}. MFMA
// mfma_f32_16x16x32_f16: A lane row=l&15, k=(l>>4)*8+j; C col=l&15,
// row=(l>>4)*4+reg [m89/m91]. Wave w K-split: h-K [w*256,+256) (8 chunks),
// x-K [w*32,+32) (q=8).
// h exchange: fp8 hb[g][slot4][rg][16 rows][1024 cols] (R12-proven code:
// byte = sign|f16bits(v/256)[13:7]; dq -> f16 worth v/256; W packed 256*W
// with k-perm P={0,2,1,3,4,6,5,7}; xT=x/256). 4 rotating slots; WAR safe by
// flag transitivity (flag[p]>=v => p's 4 waves saw all 32 flags >= v-1).
// Sync per step: stores A+B -> one __syncthreads (vmcnt0 drain) -> flag store
// -> per-wave poll of 8 producers (first iter usually hits) -> issue A(t+1)
// loads. B(t+1) loads issued after next phase-A MFMA (hidden under epilogue).

typedef _Float16 f16x8 __attribute__((ext_vector_type(8)));
typedef float f32x4 __attribute__((ext_vector_type(4)));
typedef unsigned long long u64;
typedef unsigned u32;

#define SCOPE_AGENT __HIP_MEMORY_SCOPE_AGENT

#define WS_WP    0ull
#define WS_BIAS  9437184ull
#define WS_XT    (WS_BIAS + 16384ull)
#define WS_HB    (WS_XT + 16777216ull)          // 2g x 4slot x 8rg x 16KB = 1MB
#define WS_SIGH  (WS_HB + 1048576ull)
#define WS_BAR   (WS_SIGH + 1048576ull)

__device__ __forceinline__ unsigned short f2h(float f) {
  _Float16 h = (_Float16)f;
  return __builtin_bit_cast(unsigned short, h);
}
__device__ __forceinline__ float fast_sig(float x) {
  return __builtin_amdgcn_rcpf(1.f + __expf(-x));
}
__device__ __forceinline__ float fast_tanh(float x) {
  return __builtin_fmaf(2.f, fast_sig(2.f * x), -1.f);
}
// h fp8 encode: v in (-1,1) -> byte = sign | RNE(f16bits(v/256))[13:7]
__device__ __forceinline__ unsigned char h_enc(float v) {
  _Float16 gh = (_Float16)(v * 0.00390625f);
  unsigned m = __builtin_bit_cast(unsigned short, gh);
  unsigned r = m + 0x3fu + ((m >> 7) & 1u);
  return (unsigned char)(((m >> 8) & 0x80u) | ((r >> 7) & 0x7fu));
}
// dequant 8 fp8 bytes -> f16x8 patterns worth v/256, element order
// {b0,b2,b1,b3,b4,b6,b5,b7} (W pack applies same k-permutation).
__device__ __forceinline__ f16x8 dq(u64 v) {
  unsigned w0 = (unsigned)v, w1 = (unsigned)(v >> 32);
  unsigned e0 = w0 & 0x00ff00ffu, o0 = (w0 >> 8) & 0x00ff00ffu;
  unsigned e1 = w1 & 0x00ff00ffu, o1 = (w1 >> 8) & 0x00ff00ffu;
  int4 t;
  t.x = (int)((e0 + (e0 & 0x00800080u)) << 7);
  t.y = (int)((o0 + (o0 & 0x00800080u)) << 7);
  t.z = (int)((e1 + (e1 & 0x00800080u)) << 7);
  t.w = (int)((o1 + (o1 & 0x00800080u)) << 7);
  return __builtin_bit_cast(f16x8, t);
}
// LDS-only barrier: does NOT drain vmcnt (in-flight global loads survive).
__device__ __forceinline__ void lds_barrier() {
  asm volatile("s_waitcnt lgkmcnt(0)" ::: "memory");
  __builtin_amdgcn_s_barrier();
  asm volatile("" ::: "memory");
}

// Pack 256*W_cat into per-(cg,w,ct,q,lane) 16x16x32 MFMA B-fragments (fp16).
// i = ((((cg*4 + w)*8 + ct)*9 + q)*64 + l)*8 + j
//   gcol = (ct>>1)*1024 + cg*32 + (ct&1)*16 + (l&15); khi = (l>>4)*8
//   q<8 (h, PERMUTED j): k = w*256 + q*32 + khi + P[j] -> W_hh[gcol][k]
//   q=8 (x, natural j):  f = w*32 + khi + j           -> W_ih[gcol][f]
__global__ void prep_pack(const float* __restrict__ W_ih, const float* __restrict__ W_hh,
                          const float* __restrict__ b_ih, const float* __restrict__ b_hh,
                          unsigned short* __restrict__ wp, float* __restrict__ bias) {
  unsigned i = blockIdx.x * 256u + threadIdx.x;
  if (i < 4718592u) {
    unsigned j = i & 7u;
    unsigned l = (i >> 3) & 63u;
    unsigned rest = i >> 9;
    unsigned q = rest % 9u;
    unsigned rest2 = rest / 9u;
    unsigned ct = rest2 & 7u;
    unsigned rest3 = rest2 >> 3;
    unsigned w = rest3 & 3u;
    unsigned cg = rest3 >> 2;
    unsigned gcol = (ct >> 1) * 1024u + cg * 32u + (ct & 1u) * 16u + (l & 15u);
    unsigned khi = (l >> 4) * 8u;
    float v;
    if (q < 8u) {
      unsigned pj = (0x75643120u >> (4u * j)) & 0xfu;   // {0,2,1,3,4,6,5,7}
      unsigned k = w * 256u + q * 32u + khi + pj;
      v = W_hh[(size_t)gcol * 1024u + k];
    } else {
      unsigned f = w * 32u + khi + j;
      v = W_ih[(size_t)gcol * 128u + f];
    }
    wp[i] = f2h(v * 256.0f);
  }
  if (i < 4096u) bias[i] = b_ih[i] + b_hh[i];
}

// xT[t][b][f] = fp16(x/256) ; h0 -> fp8 hb slot0 both groups ; zero flags.
__global__ void prep_misc(const float* __restrict__ x, const float* __restrict__ h0,
                          unsigned short* __restrict__ xT, unsigned char* __restrict__ hb,
                          unsigned* __restrict__ bar) {
  unsigned i = blockIdx.x * 256u + threadIdx.x;
  if (i < 8388608u) {
    unsigned f = i & 127u;
    unsigned b = (i >> 7) & 255u;
    unsigned t = i >> 15;
    xT[i] = f2h(x[((size_t)b * 256u + t) * 128u + f] * 0.00390625f);
  }
  if (i < 262144u) {
    unsigned col = i & 1023u;
    unsigned grow = i >> 10;
    unsigned g = grow >> 7;
    unsigned rg = (grow >> 4) & 7u;
    unsigned row = grow & 15u;
    hb[((g * 4u + 0u) * 8u + rg) * 16384u + row * 1024u + col] = h_enc(h0[i]);
  }
  if (i < 512u) bar[i] = 0u;
}

#define LOAD_TILE(SA, G, SLOT) do {                                              \
    const char* _b = (const char*)hb + (((G)*4u + (SLOT))*8u + rg)*16384u        \
                     + hi*1024u + w*256u + lo5*8u;                               \
    _Pragma("unroll")                                                            \
    for (int _r = 0; _r < 8; ++_r)                                               \
      SA[_r] = __hip_atomic_load((const u64*)(_b + (unsigned)_r*2048u),          \
                                 __ATOMIC_RELAXED, SCOPE_AGENT);                 \
  } while (0)

__launch_bounds__(256, 1)
__global__ void lstm_main(const unsigned short* __restrict__ wp,
                          const float* __restrict__ bias,
                          const unsigned short* __restrict__ xT,
                          unsigned char* __restrict__ hb,
                          const float* __restrict__ c0,
                          float* __restrict__ sigh,
                          unsigned* __restrict__ bar) {
  extern __shared__ char lds[];
  // [0,16K): per-wave fp8 stage (w*4KB, [16 rows][256B], kbyte^(row&15)<<3)
  // [16K,48K): redv [w4][ct8][l64] float4   [48K,56K): Sf [ct8][reg4][l64] f32
  // [56K..): hstA 512B, hstB 512B
  float4* redv = (float4*)(lds + 16384);
  float*  Sf   = (float*)(lds + 49152);
  unsigned char* hstA = (unsigned char*)(lds + 57344);
  unsigned char* hstB = (unsigned char*)(lds + 57856);

  const unsigned tid = threadIdx.x;
  const unsigned wg  = blockIdx.x;
  const unsigned w   = tid >> 6;
  const unsigned l   = tid & 63u;
  const unsigned rg  = wg >> 5;
  const unsigned cg  = wg & 31u;
  const unsigned lo5 = l & 31u;
  const unsigned hi  = l >> 5;
  const unsigned l15 = l & 15u;
  const unsigned l4  = l >> 4;
  const unsigned row = l4 * 4u + w;            // cell row 0..15 (reg = w)

  // ---- register-resident W fragments (72 x int4) ----
  int4 Braw[8][9];
  {
    const int4* wpv = (const int4*)wp;
    const unsigned wbase = (cg * 4u + w) * 4608u;
#pragma unroll
    for (int ct = 0; ct < 8; ++ct)
#pragma unroll
      for (int q = 0; q < 9; ++q)
        Braw[ct][q] = wpv[wbase + (unsigned)(ct * 9 + q) * 64u + l];
  }

  float bias_v[8];
#pragma unroll
  for (int ct = 0; ct < 8; ++ct)
    bias_v[ct] = bias[(unsigned)(ct >> 1) * 1024u + cg * 32u + (unsigned)(ct & 1) * 16u + l15];

  const unsigned gbA = rg * 16u, gbB = 128u + rg * 16u;
  float cA[2], cB[2];
  unsigned soffA[2], soffB[2];
#pragma unroll
  for (int hh = 0; hh < 2; ++hh) {
    soffA[hh] = (gbA + row) * 1024u + cg * 32u + (unsigned)hh * 16u + l15;
    soffB[hh] = (gbB + row) * 1024u + cg * 32u + (unsigned)hh * 16u + l15;
    cA[hh] = c0[soffA[hh]];
    cB[hh] = c0[soffB[hh]];
  }

  const char* xbase = (const char*)xT;
  const unsigned xoffA = ((gbA + l15) * 128u + w * 32u + l4 * 8u) * 2u;
  const unsigned xoffB = ((gbB + l15) * 128u + w * 32u + l4 * 8u) * 2u;
  unsigned* flags = &bar[rg * 32u];

  const unsigned fragrow = w * 4096u + l15 * 256u;   // frag read row base

  u64 saA[8], saB[8];
  int4 xrA, xrB;

  LOAD_TILE(saA, 0u, 0u);
  xrA = *(const int4*)(xbase + xoffA);
  xrB = *(const int4*)(xbase + xoffB);

  for (unsigned t = 0; t < 256u; ++t) {
    const bool last = (t == 255u);
    const unsigned slot = t & 3u, wslot = (t + 1u) & 3u;

    // ================= PHASE A =================
#pragma unroll
    for (int r = 0; r < 8; ++r) {
      unsigned rr = hi + 2u * (unsigned)r;
      unsigned d = w * 4096u + rr * 256u + ((lo5 * 8u) ^ ((rr & 15u) << 3));
      *(u64*)(lds + d) = saA[r];
    }
    f32x4 acc[8] = {};
    {
      f16x8 a = __builtin_bit_cast(f16x8, xrA);
#pragma unroll
      for (int ct = 0; ct < 8; ++ct)
        acc[ct] = __builtin_amdgcn_mfma_f32_16x16x32_f16(a, __builtin_bit_cast(f16x8, Braw[ct][8]), acc[ct], 0, 0, 0);
    }
#pragma unroll
    for (int q = 0; q < 8; ++q) {
      unsigned addr = fragrow + (((unsigned)q * 32u + l4 * 8u) ^ (l15 << 3));
      f16x8 a = dq(*(const u64*)(lds + addr));
#pragma unroll
      for (int ct = 0; ct < 8; ++ct)
        acc[ct] = __builtin_amdgcn_mfma_f32_16x16x32_f16(a, __builtin_bit_cast(f16x8, Braw[ct][q]), acc[ct], 0, 0, 0);
    }
    // issue B(t) loads now (flag(t) already confirmed); hidden under epilogue
    LOAD_TILE(saB, 1u, slot);

    // reduce A (conflict-free two-stage)
#pragma unroll
    for (int ct = 0; ct < 8; ++ct) {
      float4 v; v.x = acc[ct][0]; v.y = acc[ct][1]; v.z = acc[ct][2]; v.w = acc[ct][3];
      redv[(w * 8u + (unsigned)ct) * 64u + l] = v;
    }
    lds_barrier();
#pragma unroll
    for (int c2 = 0; c2 < 2; ++c2) {
      unsigned ct = 2u * w + (unsigned)c2;
      float4 s = redv[ct * 64u + l];
#pragma unroll
      for (int wo = 1; wo < 4; ++wo) {
        float4 v = redv[((unsigned)wo * 8u + ct) * 64u + l];
        s.x += v.x; s.y += v.y; s.z += v.z; s.w += v.w;
      }
      Sf[ct * 256u + 0u * 64u + l] = s.x;
      Sf[ct * 256u + 1u * 64u + l] = s.y;
      Sf[ct * 256u + 2u * 64u + l] = s.z;
      Sf[ct * 256u + 3u * 64u + l] = s.w;
    }
    lds_barrier();
    float gv[8];
#pragma unroll
    for (int ct = 0; ct < 8; ++ct)
      gv[ct] = Sf[(unsigned)ct * 256u + w * 64u + l] + bias_v[ct];
#pragma unroll
    for (int hh = 0; hh < 2; ++hh) {
      float ig = fast_sig(gv[0 * 2 + hh]);
      float fg = fast_sig(gv[1 * 2 + hh]);
      float gg = fast_tanh(gv[2 * 2 + hh]);
      float og = fast_sig(gv[3 * 2 + hh]);
      float cc = fg * cA[hh] + ig * gg;
      cA[hh] = cc;
      float hhv = og * fast_tanh(cc);
      hstA[row * 32u + (unsigned)hh * 16u + l15] = h_enc(hhv);
      if (last) sigh[soffA[hh]] = fast_sig(hhv);
    }
    lds_barrier();
    if (!last && tid < 128u) {
      u32 v = *(const u32*)(hstA + (tid >> 3) * 32u + (tid & 7u) * 4u);
      char* dst = (char*)hb + ((0u * 4u + wslot) * 8u + rg) * 16384u
                  + (tid >> 3) * 1024u + cg * 32u + (tid & 7u) * 4u;
      __hip_atomic_store((u32*)dst, v, __ATOMIC_RELAXED, SCOPE_AGENT);
    }

    // ================= PHASE B =================
#pragma unroll
    for (int r = 0; r < 8; ++r) {
      unsigned rr = hi + 2u * (unsigned)r;
      unsigned d = w * 4096u + rr * 256u + ((lo5 * 8u) ^ ((rr & 15u) << 3));
      *(u64*)(lds + d) = saB[r];
    }
    f32x4 accB[8] = {};
    {
      f16x8 a = __builtin_bit_cast(f16x8, xrB);
#pragma unroll
      for (int ct = 0; ct < 8; ++ct)
        accB[ct] = __builtin_amdgcn_mfma_f32_16x16x32_f16(a, __builtin_bit_cast(f16x8, Braw[ct][8]), accB[ct], 0, 0, 0);
    }
#pragma unroll
    for (int q = 0; q < 8; ++q) {
      unsigned addr = fragrow + (((unsigned)q * 32u + l4 * 8u) ^ (l15 << 3));
      f16x8 a = dq(*(const u64*)(lds + addr));
#pragma unroll
      for (int ct = 0; ct < 8; ++ct)
        accB[ct] = __builtin_amdgcn_mfma_f32_16x16x32_f16(a, __builtin_bit_cast(f16x8, Braw[ct][q]), accB[ct], 0, 0, 0);
    }
    if (!last) {   // x prefetch for t+1 (no sync dependency)
      xrA = *(const int4*)(xbase + xoffA + (t + 1u) * 65536u);
      xrB = *(const int4*)(xbase + xoffB + (t + 1u) * 65536u);
    }

#pragma unroll
    for (int ct = 0; ct < 8; ++ct) {
      float4 v; v.x = accB[ct][0]; v.y = accB[ct][1]; v.z = accB[ct][2]; v.w = accB[ct][3];
      redv[(w * 8u + (unsigned)ct) * 64u + l] = v;
    }
    lds_barrier();
#pragma unroll
    for (int c2 = 0; c2 < 2; ++c2) {
      unsigned ct = 2u * w + (unsigned)c2;
      float4 s = redv[ct * 64u + l];
#pragma unroll
      for (int wo = 1; wo < 4; ++wo) {
        float4 v = redv[((unsigned)wo * 8u + ct) * 64u + l];
        s.x += v.x; s.y += v.y; s.z += v.z; s.w += v.w;
      }
      Sf[ct * 256u + 0u * 64u + l] = s.x;
      Sf[ct * 256u + 1u * 64u + l] = s.y;
      Sf[ct * 256u + 2u * 64u + l] = s.z;
      Sf[ct * 256u + 3u * 64u + l] = s.w;
    }
    lds_barrier();
#pragma unroll
    for (int ct = 0; ct < 8; ++ct)
      gv[ct] = Sf[(unsigned)ct * 256u + w * 64u + l] + bias_v[ct];
#pragma unroll
    for (int hh = 0; hh < 2; ++hh) {
      float ig = fast_sig(gv[0 * 2 + hh]);
      float fg = fast_sig(gv[1 * 2 + hh]);
      float gg = fast_tanh(gv[2 * 2 + hh]);
      float og = fast_sig(gv[3 * 2 + hh]);
      float cc = fg * cB[hh] + ig * gg;
      cB[hh] = cc;
      float hhv = og * fast_tanh(cc);
      hstB[row * 32u + (unsigned)hh * 16u + l15] = h_enc(hhv);
      if (last) sigh[soffB[hh]] = fast_sig(hhv);
    }
    lds_barrier();
    if (!last) {
      if (tid < 128u) {
        u32 v = *(const u32*)(hstB + (tid >> 3) * 32u + (tid & 7u) * 4u);
        char* dst = (char*)hb + ((1u * 4u + wslot) * 8u + rg) * 16384u
                    + (tid >> 3) * 1024u + cg * 32u + (tid & 7u) * 4u;
        __hip_atomic_store((u32*)dst, v, __ATOMIC_RELAXED, SCOPE_AGENT);
      }
      __syncthreads();   // ONE full vmcnt drain per step: A+B stores at MALL
      if (tid == 0)
        __hip_atomic_store(&flags[cg], t + 1u, __ATOMIC_RELAXED, SCOPE_AGENT);
      {  // per-wave poll of this wave's 8 producers
        const unsigned tgt = t + 1u;
        for (;;) {
          unsigned f = __hip_atomic_load(&flags[w * 8u + (l & 7u)],
                                         __ATOMIC_RELAXED, SCOPE_AGENT);
          if (__all(f >= tgt)) break;
          __builtin_amdgcn_s_sleep(1);
        }
      }
      LOAD_TILE(saA, 0u, wslot);   // A(t+1); latency hidden under loop top
    }
  }
}

// out[b][o] = b_fc[o] + sum_k sigh[b][k] * W_fc[o][k]
__global__ void final_fc(const float* __restrict__ sigh, const float* __restrict__ W_fc,
                         const float* __restrict__ b_fc, float* __restrict__ out) {
  unsigned b = blockIdx.x;
  unsigned o = threadIdx.x;
  const float* hrow = sigh + (size_t)b * 1024u;
  const float* wrow = W_fc + (size_t)o * 1024u;
  float acc = b_fc[o];
#pragma unroll 8
  for (unsigned k = 0; k < 1024u; k += 4u) {
    float4 hv = *(const float4*)(hrow + k);
    float4 wv = *(const float4*)(wrow + k);
    acc += hv.x * wv.x + hv.y * wv.y + hv.z * wv.z + hv.w * wv.w;
  }
  out[b * 128u + o] = acc;
}

extern "C" void kernel_launch(void* const* d_in, const int* in_sizes, int n_in,
                              void* d_out, int out_size, void* d_ws, size_t ws_size,
                              hipStream_t stream) {
  (void)in_sizes; (void)n_in; (void)out_size; (void)ws_size;
  const float* x    = (const float*)d_in[0];
  const float* h0   = (const float*)d_in[1];
  const float* c0   = (const float*)d_in[2];
  const float* W_ih = (const float*)d_in[3];
  const float* W_hh = (const float*)d_in[4];
  const float* b_ih = (const float*)d_in[5];
  const float* b_hh = (const float*)d_in[6];
  const float* W_fc = (const float*)d_in[7];
  const float* b_fc = (const float*)d_in[8];

  char* ws = (char*)d_ws;
  unsigned short* wp   = (unsigned short*)(ws + WS_WP);
  float*          bias = (float*)(ws + WS_BIAS);
  unsigned short* xT   = (unsigned short*)(ws + WS_XT);
  unsigned char*  hb   = (unsigned char*)(ws + WS_HB);
  float*          sigh = (float*)(ws + WS_SIGH);
  unsigned*       bar  = (unsigned*)(ws + WS_BAR);
  float*          out  = (float*)d_out;

  prep_pack<<<18432, 256, 0, stream>>>(W_ih, W_hh, b_ih, b_hh, wp, bias);
  prep_misc<<<32768, 256, 0, stream>>>(x, h0, xT, hb, bar);
  lstm_main<<<256, 256, 58368, stream>>>(wp, bias, xT, hb, c0, sigh, bar);
  final_fc<<<256, 128, 0, stream>>>(sigh, W_fc, b_fc, out);
}